// Round 1
// baseline (46822.327 us; speedup 1.0000x reference)
//
#include <hip/hip_runtime.h>
#include <hip/hip_bf16.h>
#include <cstddef>

// Problem constants (from reference)
#define B     64
#define S     256
#define E     640
#define H     512
#define TSTEPS (S - 1)     // 255
#define G4    (4 * H)      // 2048
#define ZDIM  4096
#define KT    64           // K-chunk staged in LDS

__device__ __forceinline__ float sigf(float x) { return 1.0f / (1.0f + __expf(-x)); }

// ---------------------------------------------------------------------------
// Layer-0 step: for dir d, gate-col j: g = x @ wih.T + h @ whh.T + b; update h,c
// grid (128, 2), block 256.  thread: b = tid&63, j = blockIdx.x*4 + (tid>>6)
// ---------------------------------------------------------------------------
__global__ __launch_bounds__(256) void lstm_l0_step(
    const float* __restrict__ x,      // (B,E) at timestep t
    const float* __restrict__ wih,    // (2,2048,E)
    const float* __restrict__ whh,    // (2,2048,H)
    const float* __restrict__ bih,    // (2,2048)
    const float* __restrict__ bhh,    // (2,2048)
    const float* __restrict__ hprev,  // (4,B,H)
    float*       hnext,               // (4,B,H)
    float*       cbuf)                // (4,B,H)
{
    const int d   = blockIdx.y;
    const int tid = threadIdx.x;
    const int b   = tid & 63;
    const int j   = blockIdx.x * 4 + (tid >> 6);

    __shared__ float xs[KT][B + 1];   // staged source chunk, transposed [k][b]

    float acc0 = 0.f, acc1 = 0.f, acc2 = 0.f, acc3 = 0.f;

    // ---- input part: K = E -------------------------------------------------
    {
        const float* w0 = wih + ((size_t)d * G4 + 0 * H + j) * E;
        const float* w1 = wih + ((size_t)d * G4 + 1 * H + j) * E;
        const float* w2 = wih + ((size_t)d * G4 + 2 * H + j) * E;
        const float* w3 = wih + ((size_t)d * G4 + 3 * H + j) * E;
        for (int k0 = 0; k0 < E; k0 += KT) {
            __syncthreads();
            for (int idx = tid; idx < (B * KT) / 4; idx += 256) {
                int bb = idx / (KT / 4);
                int kq = idx % (KT / 4);
                float4 v = *(const float4*)(x + (size_t)bb * E + k0 + kq * 4);
                xs[kq * 4 + 0][bb] = v.x; xs[kq * 4 + 1][bb] = v.y;
                xs[kq * 4 + 2][bb] = v.z; xs[kq * 4 + 3][bb] = v.w;
            }
            __syncthreads();
            #pragma unroll
            for (int k = 0; k < KT; k += 4) {
                float4 a0 = *(const float4*)(w0 + k0 + k);
                float4 a1 = *(const float4*)(w1 + k0 + k);
                float4 a2 = *(const float4*)(w2 + k0 + k);
                float4 a3 = *(const float4*)(w3 + k0 + k);
                float x0 = xs[k + 0][b], x1 = xs[k + 1][b];
                float x2 = xs[k + 2][b], x3 = xs[k + 3][b];
                acc0 += a0.x * x0 + a0.y * x1 + a0.z * x2 + a0.w * x3;
                acc1 += a1.x * x0 + a1.y * x1 + a1.z * x2 + a1.w * x3;
                acc2 += a2.x * x0 + a2.y * x1 + a2.z * x2 + a2.w * x3;
                acc3 += a3.x * x0 + a3.y * x1 + a3.z * x2 + a3.w * x3;
            }
        }
    }
    // ---- hidden part: K = H, source hprev cell d ---------------------------
    {
        const float* hp = hprev + (size_t)d * B * H;
        const float* w0 = whh + ((size_t)d * G4 + 0 * H + j) * H;
        const float* w1 = whh + ((size_t)d * G4 + 1 * H + j) * H;
        const float* w2 = whh + ((size_t)d * G4 + 2 * H + j) * H;
        const float* w3 = whh + ((size_t)d * G4 + 3 * H + j) * H;
        for (int k0 = 0; k0 < H; k0 += KT) {
            __syncthreads();
            for (int idx = tid; idx < (B * KT) / 4; idx += 256) {
                int bb = idx / (KT / 4);
                int kq = idx % (KT / 4);
                float4 v = *(const float4*)(hp + (size_t)bb * H + k0 + kq * 4);
                xs[kq * 4 + 0][bb] = v.x; xs[kq * 4 + 1][bb] = v.y;
                xs[kq * 4 + 2][bb] = v.z; xs[kq * 4 + 3][bb] = v.w;
            }
            __syncthreads();
            #pragma unroll
            for (int k = 0; k < KT; k += 4) {
                float4 a0 = *(const float4*)(w0 + k0 + k);
                float4 a1 = *(const float4*)(w1 + k0 + k);
                float4 a2 = *(const float4*)(w2 + k0 + k);
                float4 a3 = *(const float4*)(w3 + k0 + k);
                float x0 = xs[k + 0][b], x1 = xs[k + 1][b];
                float x2 = xs[k + 2][b], x3 = xs[k + 3][b];
                acc0 += a0.x * x0 + a0.y * x1 + a0.z * x2 + a0.w * x3;
                acc1 += a1.x * x0 + a1.y * x1 + a1.z * x2 + a1.w * x3;
                acc2 += a2.x * x0 + a2.y * x1 + a2.z * x2 + a2.w * x3;
                acc3 += a3.x * x0 + a3.y * x1 + a3.z * x2 + a3.w * x3;
            }
        }
    }
    // ---- bias + activations + state update --------------------------------
    acc0 += bih[(size_t)d * G4 + 0 * H + j] + bhh[(size_t)d * G4 + 0 * H + j];
    acc1 += bih[(size_t)d * G4 + 1 * H + j] + bhh[(size_t)d * G4 + 1 * H + j];
    acc2 += bih[(size_t)d * G4 + 2 * H + j] + bhh[(size_t)d * G4 + 2 * H + j];
    acc3 += bih[(size_t)d * G4 + 3 * H + j] + bhh[(size_t)d * G4 + 3 * H + j];

    size_t o = ((size_t)d * B + b) * H + j;
    float cold = cbuf[o];
    float cnew = sigf(acc1) * cold + sigf(acc0) * tanhf(acc2);
    float hnew = sigf(acc3) * tanhf(cnew);
    cbuf[o]  = cnew;
    hnext[o] = hnew;
}

// ---------------------------------------------------------------------------
// Layer-1 step: x = concat(hnext cell0, hnext cell1)  (K=1024), hidden K=512
// cells 2+d.  grid (128,2), block 256.
// ---------------------------------------------------------------------------
__global__ __launch_bounds__(256) void lstm_l1_step(
    const float* __restrict__ wih,    // (2,2048,1024)
    const float* __restrict__ whh,    // (2,2048,512)
    const float* __restrict__ bih,    // (2,2048)
    const float* __restrict__ bhh,    // (2,2048)
    const float* __restrict__ hprev,  // (4,B,H)
    float*       hnext,               // (4,B,H): read cells 0,1; write 2+d
    float*       cbuf)                // (4,B,H)
{
    const int d   = blockIdx.y;
    const int tid = threadIdx.x;
    const int b   = tid & 63;
    const int j   = blockIdx.x * 4 + (tid >> 6);
    const int KX  = 2 * H;            // 1024

    __shared__ float xs[KT][B + 1];

    float acc0 = 0.f, acc1 = 0.f, acc2 = 0.f, acc3 = 0.f;

    // ---- input part: K = 1024 (concat of layer-0 outputs this step) -------
    {
        const float* w0 = wih + ((size_t)d * G4 + 0 * H + j) * KX;
        const float* w1 = wih + ((size_t)d * G4 + 1 * H + j) * KX;
        const float* w2 = wih + ((size_t)d * G4 + 2 * H + j) * KX;
        const float* w3 = wih + ((size_t)d * G4 + 3 * H + j) * KX;
        for (int k0 = 0; k0 < KX; k0 += KT) {
            const int cell = (k0 >= H) ? 1 : 0;
            const float* src = hnext + (size_t)cell * B * H + (k0 - cell * H);
            __syncthreads();
            for (int idx = tid; idx < (B * KT) / 4; idx += 256) {
                int bb = idx / (KT / 4);
                int kq = idx % (KT / 4);
                float4 v = *(const float4*)(src + (size_t)bb * H + kq * 4);
                xs[kq * 4 + 0][bb] = v.x; xs[kq * 4 + 1][bb] = v.y;
                xs[kq * 4 + 2][bb] = v.z; xs[kq * 4 + 3][bb] = v.w;
            }
            __syncthreads();
            #pragma unroll
            for (int k = 0; k < KT; k += 4) {
                float4 a0 = *(const float4*)(w0 + k0 + k);
                float4 a1 = *(const float4*)(w1 + k0 + k);
                float4 a2 = *(const float4*)(w2 + k0 + k);
                float4 a3 = *(const float4*)(w3 + k0 + k);
                float x0 = xs[k + 0][b], x1 = xs[k + 1][b];
                float x2 = xs[k + 2][b], x3 = xs[k + 3][b];
                acc0 += a0.x * x0 + a0.y * x1 + a0.z * x2 + a0.w * x3;
                acc1 += a1.x * x0 + a1.y * x1 + a1.z * x2 + a1.w * x3;
                acc2 += a2.x * x0 + a2.y * x1 + a2.z * x2 + a2.w * x3;
                acc3 += a3.x * x0 + a3.y * x1 + a3.z * x2 + a3.w * x3;
            }
        }
    }
    // ---- hidden part: K = H, source hprev cell 2+d -------------------------
    {
        const float* hp = hprev + (size_t)(2 + d) * B * H;
        const float* w0 = whh + ((size_t)d * G4 + 0 * H + j) * H;
        const float* w1 = whh + ((size_t)d * G4 + 1 * H + j) * H;
        const float* w2 = whh + ((size_t)d * G4 + 2 * H + j) * H;
        const float* w3 = whh + ((size_t)d * G4 + 3 * H + j) * H;
        for (int k0 = 0; k0 < H; k0 += KT) {
            __syncthreads();
            for (int idx = tid; idx < (B * KT) / 4; idx += 256) {
                int bb = idx / (KT / 4);
                int kq = idx % (KT / 4);
                float4 v = *(const float4*)(hp + (size_t)bb * H + k0 + kq * 4);
                xs[kq * 4 + 0][bb] = v.x; xs[kq * 4 + 1][bb] = v.y;
                xs[kq * 4 + 2][bb] = v.z; xs[kq * 4 + 3][bb] = v.w;
            }
            __syncthreads();
            #pragma unroll
            for (int k = 0; k < KT; k += 4) {
                float4 a0 = *(const float4*)(w0 + k0 + k);
                float4 a1 = *(const float4*)(w1 + k0 + k);
                float4 a2 = *(const float4*)(w2 + k0 + k);
                float4 a3 = *(const float4*)(w3 + k0 + k);
                float x0 = xs[k + 0][b], x1 = xs[k + 1][b];
                float x2 = xs[k + 2][b], x3 = xs[k + 3][b];
                acc0 += a0.x * x0 + a0.y * x1 + a0.z * x2 + a0.w * x3;
                acc1 += a1.x * x0 + a1.y * x1 + a1.z * x2 + a1.w * x3;
                acc2 += a2.x * x0 + a2.y * x1 + a2.z * x2 + a2.w * x3;
                acc3 += a3.x * x0 + a3.y * x1 + a3.z * x2 + a3.w * x3;
            }
        }
    }
    // ---- bias + activations + state update --------------------------------
    acc0 += bih[(size_t)d * G4 + 0 * H + j] + bhh[(size_t)d * G4 + 0 * H + j];
    acc1 += bih[(size_t)d * G4 + 1 * H + j] + bhh[(size_t)d * G4 + 1 * H + j];
    acc2 += bih[(size_t)d * G4 + 2 * H + j] + bhh[(size_t)d * G4 + 2 * H + j];
    acc3 += bih[(size_t)d * G4 + 3 * H + j] + bhh[(size_t)d * G4 + 3 * H + j];

    size_t o = ((size_t)(2 + d) * B + b) * H + j;
    float cold = cbuf[o];
    float cnew = sigf(acc1) * cold + sigf(acc0) * tanhf(acc2);
    float hnew = sigf(acc3) * tanhf(cnew);
    cbuf[o]  = cnew;
    hnext[o] = hnew;
}

// ---------------------------------------------------------------------------
// Head: z = ziphidden(hF,cF); out = z@Wmu.T + bmu + eps*exp(0.5*(z@Wvar.T+bvar))
// grid (1024), block 256. thread: b = tid&63, i = blockIdx.x*4 + (tid>>6)
// ---------------------------------------------------------------------------
__global__ __launch_bounds__(256) void head_kernel(
    const float* __restrict__ hF,     // (4,B,H)
    const float* __restrict__ cF,     // (4,B,H)
    const float* __restrict__ eps,    // (B,ZDIM)
    const float* __restrict__ Wmu,    // (ZDIM,ZDIM)
    const float* __restrict__ bmu,    // (ZDIM)
    const float* __restrict__ Wvar,   // (ZDIM,ZDIM)
    const float* __restrict__ bvar,   // (ZDIM)
    float* __restrict__ out)          // (B,ZDIM)
{
    const int tid = threadIdx.x;
    const int b   = tid & 63;
    const int i   = blockIdx.x * 4 + (tid >> 6);

    __shared__ float zs[KT][B + 1];

    float amu = 0.f, alv = 0.f;
    const float* wm = Wmu  + (size_t)i * ZDIM;
    const float* wv = Wvar + (size_t)i * ZDIM;

    for (int k0 = 0; k0 < ZDIM; k0 += KT) {
        const int cell = k0 >> 10;            // which of the 4 (h|c) blocks
        const int m    = k0 & 1023;           // offset within the 1024 block
        const float* src = (m < H) ? (hF + (size_t)cell * B * H + m)
                                   : (cF + (size_t)cell * B * H + (m - H));
        __syncthreads();
        for (int idx = tid; idx < (B * KT) / 4; idx += 256) {
            int bb = idx / (KT / 4);
            int kq = idx % (KT / 4);
            float4 v = *(const float4*)(src + (size_t)bb * H + kq * 4);
            zs[kq * 4 + 0][bb] = v.x; zs[kq * 4 + 1][bb] = v.y;
            zs[kq * 4 + 2][bb] = v.z; zs[kq * 4 + 3][bb] = v.w;
        }
        __syncthreads();
        #pragma unroll
        for (int k = 0; k < KT; k += 4) {
            float4 a = *(const float4*)(wm + k0 + k);
            float4 c = *(const float4*)(wv + k0 + k);
            float z0 = zs[k + 0][b], z1 = zs[k + 1][b];
            float z2 = zs[k + 2][b], z3 = zs[k + 3][b];
            amu += a.x * z0 + a.y * z1 + a.z * z2 + a.w * z3;
            alv += c.x * z0 + c.y * z1 + c.z * z2 + c.w * z3;
        }
    }
    float mu = amu + bmu[i];
    float lv = alv + bvar[i];
    out[(size_t)b * ZDIM + i] = mu + eps[(size_t)b * ZDIM + i] * __expf(0.5f * lv);
}

// ---------------------------------------------------------------------------
extern "C" void kernel_launch(void* const* d_in, const int* in_sizes, int n_in,
                              void* d_out, int out_size, void* d_ws, size_t ws_size,
                              hipStream_t stream) {
    const float* input = (const float*)d_in[0];
    const float* eps   = (const float*)d_in[1];
    const float* w_ih0 = (const float*)d_in[2];
    const float* w_hh0 = (const float*)d_in[3];
    const float* b_ih0 = (const float*)d_in[4];
    const float* b_hh0 = (const float*)d_in[5];
    const float* w_ih1 = (const float*)d_in[6];
    const float* w_hh1 = (const float*)d_in[7];
    const float* b_ih1 = (const float*)d_in[8];
    const float* b_hh1 = (const float*)d_in[9];
    const float* W_mu  = (const float*)d_in[10];
    const float* b_mu  = (const float*)d_in[11];
    const float* W_var = (const float*)d_in[12];
    const float* b_var = (const float*)d_in[13];
    float* out = (float*)d_out;

    float* ws = (float*)d_ws;
    const size_t cellsz = (size_t)4 * B * H;   // floats per state array
    float* hA = ws;
    float* hB = ws + cellsz;
    float* cb = ws + 2 * cellsz;

    // zero-init h (both buffers) and c every call (deterministic)
    hipMemsetAsync(d_ws, 0, 3 * cellsz * sizeof(float), stream);

    float* hin  = hA;
    float* hout = hB;
    for (int t = 0; t < TSTEPS; ++t) {
        const float* xt = input + (size_t)t * B * E;
        lstm_l0_step<<<dim3(128, 2), 256, 0, stream>>>(
            xt, w_ih0, w_hh0, b_ih0, b_hh0, hin, hout, cb);
        lstm_l1_step<<<dim3(128, 2), 256, 0, stream>>>(
            w_ih1, w_hh1, b_ih1, b_hh1, hin, hout, cb);
        float* tmp = hin; hin = hout; hout = tmp;
    }
    // final states now in hin (and cb)
    head_kernel<<<dim3(ZDIM / 4), 256, 0, stream>>>(
        hin, cb, eps, W_mu, b_mu, W_var, b_var, out);
}

// Round 2
// 6224.540 us; speedup vs baseline: 7.5222x; 7.5222x over previous
//
#include <hip/hip_runtime.h>
#include <hip/hip_bf16.h>
#include <cstddef>
#include <cstdint>

#define B     64
#define S     256
#define E     640
#define H     512
#define TSTEPS (S - 1)       // 255
#define ZDIM  4096
#define KT    64
#define HS    (B * H)        // elems per state cell (32768)

typedef __attribute__((ext_vector_type(8))) __bf16 bf16x8;
typedef __attribute__((ext_vector_type(4))) float  f32x4;

__device__ __forceinline__ float sigf(float x) { return 1.0f / (1.0f + __expf(-x)); }

__device__ __forceinline__ unsigned short f2bf(float f) {
    union { float f; unsigned u; } x; x.f = f;
    unsigned r = x.u + 0x7fffu + ((x.u >> 16) & 1u);   // RNE
    return (unsigned short)(r >> 16);
}
__device__ __forceinline__ float bf2f(unsigned short u) {
    union { unsigned u; float f; } x; x.u = ((unsigned)u) << 16;
    return x.f;
}

// ---------------------------------------------------------------------------
// Prep kernels (run every call; deterministic)
// ---------------------------------------------------------------------------
__global__ __launch_bounds__(256) void conv_x_kernel(
    const float* __restrict__ in, unsigned short* __restrict__ out, int n8)
{
    int i = blockIdx.x * 256 + threadIdx.x;
    if (i >= n8) return;
    const float4* p = (const float4*)(in + (size_t)i * 8);
    float4 a = p[0], b = p[1];
    unsigned short* o = out + (size_t)i * 8;
    o[0] = f2bf(a.x); o[1] = f2bf(a.y); o[2] = f2bf(a.z); o[3] = f2bf(a.w);
    o[4] = f2bf(b.x); o[5] = f2bf(b.y); o[6] = f2bf(b.z); o[7] = f2bf(b.w);
}

// out[d][n][k] = in[d][(n&3)*512 + (n>>2)][k], bf16  (gate-minor packing)
__global__ __launch_bounds__(256) void repack_w_kernel(
    const float* __restrict__ in, unsigned short* __restrict__ out, int K)
{
    int kc = K / 8;
    int i = blockIdx.x * 256 + threadIdx.x;
    if (i >= 2 * 2048 * kc) return;
    int k8 = i % kc;
    int n  = (i / kc) & 2047;
    int d  = i / (kc * 2048);
    int srow = (n & 3) * 512 + (n >> 2);
    const float* src = in + ((size_t)d * 2048 + srow) * K + (size_t)k8 * 8;
    unsigned short* dst = out + ((size_t)d * 2048 + n) * K + (size_t)k8 * 8;
    #pragma unroll
    for (int q = 0; q < 8; ++q) dst[q] = f2bf(src[q]);
}

__global__ __launch_bounds__(256) void pack_bias_kernel(
    const float* __restrict__ bih, const float* __restrict__ bhh, float* __restrict__ out)
{
    int i = blockIdx.x * 256 + threadIdx.x;   // 4096
    if (i >= 4096) return;
    int d = i >> 11, n = i & 2047;
    int s = d * 2048 + (n & 3) * 512 + (n >> 2);
    out[i] = bih[s] + bhh[s];
}

// ---------------------------------------------------------------------------
// MFMA K-segment: lane-preoffset pointers, advance by 32 bf16 per iter
// ---------------------------------------------------------------------------
template<int KLEN>
__device__ __forceinline__ void seg_mm(const unsigned short* __restrict__ A,
                                       const unsigned short* __restrict__ W0,
                                       const unsigned short* __restrict__ W1,
                                       f32x4& acc0, f32x4& acc1)
{
    #pragma unroll 4
    for (int k0 = 0; k0 < KLEN; k0 += 32) {
        bf16x8 a  = *(const bf16x8*)(A  + k0);
        bf16x8 b0 = *(const bf16x8*)(W0 + k0);
        bf16x8 b1 = *(const bf16x8*)(W1 + k0);
        acc0 = __builtin_amdgcn_mfma_f32_16x16x32_bf16(a, b0, acc0, 0, 0, 0);
        acc1 = __builtin_amdgcn_mfma_f32_16x16x32_bf16(a, b1, acc1, 0, 0, 0);
    }
}

__device__ __forceinline__ float pick4(int x, float v0, float v1, float v2, float v3) {
    float a = (x & 1) ? v1 : v0;
    float b = (x & 1) ? v3 : v2;
    return (x & 2) ? b : a;
}

// Activations + state update for one wave's 2 fragments (gate-minor packed cols)
__device__ __forceinline__ void act_update(
    f32x4 acc0, f32x4 acc1, int n0, int row0, int l,
    float* __restrict__ cc, unsigned short* __restrict__ hh)
{
    const int g = l & 3;
    const int rbase = row0 + ((l >> 4) << 2);
    #pragma unroll
    for (int f = 0; f < 2; ++f) {
        f32x4 acc = f ? acc1 : acc0;
        int cp   = n0 + f * 16 + (l & 15);
        int unit = cp >> 2;
        #pragma unroll
        for (int r = 0; r < 4; ++r) {
            float v  = acc[r];
            float v1 = __shfl_xor(v, 1);
            float v2 = __shfl_xor(v, 2);
            float v3 = __shfl_xor(v, 3);
            float iv = pick4(g ^ 0, v, v1, v2, v3);
            float fv = pick4(g ^ 1, v, v1, v2, v3);
            float gv = pick4(g ^ 2, v, v1, v2, v3);
            float ov = pick4(g ^ 3, v, v1, v2, v3);
            int row = rbase + r;
            size_t o = (size_t)row * H + unit;
            float cold = cc[o];
            float cnew = sigf(fv) * cold + sigf(iv) * tanhf(gv);
            float hnew = sigf(ov) * tanhf(cnew);
            if (g == 0) { cc[o] = cnew; hh[o] = f2bf(hnew); }
        }
    }
}

// ---------------------------------------------------------------------------
// Fused pipelined step: blocks 0..127 -> L0(t=k);  128..255 -> L1(t=k-1)
// Block tile: 64 batch rows x 32 packed cols (8 units x 4 gates).
// Wave w: rows 16w..16w+15, all 32 cols (2 MFMA col-fragments).
// ---------------------------------------------------------------------------
__global__ __launch_bounds__(256) void step_kernel(
    const unsigned short* __restrict__ xb,    // (255,64,640) bf16
    const unsigned short* __restrict__ w0p,   // (2,2048,640)
    const unsigned short* __restrict__ wh0p,  // (2,2048,512)
    const unsigned short* __restrict__ w1p,   // (2,2048,1024)
    const unsigned short* __restrict__ wh1p,  // (2,2048,512)
    const float* __restrict__ b0p,            // (2,2048)
    const float* __restrict__ b1p,
    unsigned short* __restrict__ hbuf,        // (2 bufs,4 cells,64,512) bf16
    float* __restrict__ cbuf,                 // (4,64,512) fp32
    int k)
{
    const int tid = threadIdx.x;
    const int l   = tid & 63;
    const int w   = tid >> 6;
    const int lr  = l & 15;
    const int kq  = (l >> 4) * 8;
    const int cur = k & 1, nxt = cur ^ 1;
    const int row0 = w * 16;

    int bid = blockIdx.x;
    if (bid < 128) {
        if (k > TSTEPS - 1) return;           // L0 active for k=0..254
        int d = bid >> 6, ct = bid & 63, n0 = ct * 32;
        float bb0 = b0p[d * 2048 + n0 + lr];
        float bb1 = b0p[d * 2048 + n0 + 16 + lr];
        f32x4 acc0 = {bb0, bb0, bb0, bb0};
        f32x4 acc1 = {bb1, bb1, bb1, bb1};
        {   // input segment: x_t (K=640)
            const unsigned short* A  = xb + (size_t)k * B * E + (size_t)(row0 + lr) * E + kq;
            const unsigned short* W0 = w0p + ((size_t)d * 2048 + n0 + lr) * E + kq;
            const unsigned short* W1 = w0p + ((size_t)d * 2048 + n0 + 16 + lr) * E + kq;
            seg_mm<E>(A, W0, W1, acc0, acc1);
        }
        {   // hidden segment: h0 prev (K=512)
            const unsigned short* A  = hbuf + ((size_t)cur * 4 + d) * HS + (size_t)(row0 + lr) * H + kq;
            const unsigned short* W0 = wh0p + ((size_t)d * 2048 + n0 + lr) * H + kq;
            const unsigned short* W1 = wh0p + ((size_t)d * 2048 + n0 + 16 + lr) * H + kq;
            seg_mm<H>(A, W0, W1, acc0, acc1);
        }
        act_update(acc0, acc1, n0, row0, l,
                   cbuf + (size_t)d * HS,
                   hbuf + ((size_t)nxt * 4 + d) * HS);
    } else {
        if (k < 1) return;                    // L1 active for k=1..255 (t=k-1)
        int b2 = bid - 128;
        int d = b2 >> 6, ct = b2 & 63, n0 = ct * 32;
        float bb0 = b1p[d * 2048 + n0 + lr];
        float bb1 = b1p[d * 2048 + n0 + 16 + lr];
        f32x4 acc0 = {bb0, bb0, bb0, bb0};
        f32x4 acc1 = {bb1, bb1, bb1, bb1};
        {   // input seg A: h0 fwd (cell 0), W k-cols [0,512)
            const unsigned short* A  = hbuf + ((size_t)cur * 4 + 0) * HS + (size_t)(row0 + lr) * H + kq;
            const unsigned short* W0 = w1p + ((size_t)d * 2048 + n0 + lr) * 1024 + kq;
            const unsigned short* W1 = w1p + ((size_t)d * 2048 + n0 + 16 + lr) * 1024 + kq;
            seg_mm<H>(A, W0, W1, acc0, acc1);
        }
        {   // input seg B: h0 rev (cell 1), W k-cols [512,1024)
            const unsigned short* A  = hbuf + ((size_t)cur * 4 + 1) * HS + (size_t)(row0 + lr) * H + kq;
            const unsigned short* W0 = w1p + ((size_t)d * 2048 + n0 + lr) * 1024 + 512 + kq;
            const unsigned short* W1 = w1p + ((size_t)d * 2048 + n0 + 16 + lr) * 1024 + 512 + kq;
            seg_mm<H>(A, W0, W1, acc0, acc1);
        }
        {   // hidden seg: h1 prev (cell 2+d)
            const unsigned short* A  = hbuf + ((size_t)cur * 4 + 2 + d) * HS + (size_t)(row0 + lr) * H + kq;
            const unsigned short* W0 = wh1p + ((size_t)d * 2048 + n0 + lr) * H + kq;
            const unsigned short* W1 = wh1p + ((size_t)d * 2048 + n0 + 16 + lr) * H + kq;
            seg_mm<H>(A, W0, W1, acc0, acc1);
        }
        act_update(acc0, acc1, n0, row0, l,
                   cbuf + (size_t)(2 + d) * HS,
                   hbuf + ((size_t)nxt * 4 + 2 + d) * HS);
    }
}

// ---------------------------------------------------------------------------
// Head (fp32 VALU; z sourced from bf16 h (mixed final bufs) + fp32 c)
// Final h cells 0,1 live in hbuf[1]; cells 2,3 in hbuf[0].
// ---------------------------------------------------------------------------
__global__ __launch_bounds__(256) void head_kernel(
    const unsigned short* __restrict__ hbuf,
    const float* __restrict__ cbuf,
    const float* __restrict__ eps,
    const float* __restrict__ Wmu,  const float* __restrict__ bmu,
    const float* __restrict__ Wvar, const float* __restrict__ bvar,
    float* __restrict__ out)
{
    const int tid = threadIdx.x;
    const int b   = tid & 63;
    const int i   = blockIdx.x * 4 + (tid >> 6);

    __shared__ float zs[KT][B + 1];

    float amu = 0.f, alv = 0.f;
    const float* wm = Wmu  + (size_t)i * ZDIM;
    const float* wv = Wvar + (size_t)i * ZDIM;

    for (int k0 = 0; k0 < ZDIM; k0 += KT) {
        __syncthreads();
        for (int idx = tid; idx < (B * KT) / 4; idx += 256) {
            int bb  = idx / (KT / 4);
            int kq4 = (idx % (KT / 4)) * 4;
            int zk  = k0 + kq4;
            int cell = zk >> 10;
            int m    = zk & 1023;
            float4 v;
            if (m < H) {
                const unsigned short* hs = hbuf
                    + (((size_t)((cell < 2) ? 1 : 0)) * 4 + cell) * HS
                    + (size_t)bb * H + m;
                v.x = bf2f(hs[0]); v.y = bf2f(hs[1]); v.z = bf2f(hs[2]); v.w = bf2f(hs[3]);
            } else {
                v = *(const float4*)(cbuf + (size_t)cell * HS + (size_t)bb * H + (m - H));
            }
            zs[kq4 + 0][bb] = v.x; zs[kq4 + 1][bb] = v.y;
            zs[kq4 + 2][bb] = v.z; zs[kq4 + 3][bb] = v.w;
        }
        __syncthreads();
        #pragma unroll
        for (int kk = 0; kk < KT; kk += 4) {
            float4 a = *(const float4*)(wm + k0 + kk);
            float4 c = *(const float4*)(wv + k0 + kk);
            float z0 = zs[kk + 0][b], z1 = zs[kk + 1][b];
            float z2 = zs[kk + 2][b], z3 = zs[kk + 3][b];
            amu += a.x * z0 + a.y * z1 + a.z * z2 + a.w * z3;
            alv += c.x * z0 + c.y * z1 + c.z * z2 + c.w * z3;
        }
    }
    float mu = amu + bmu[i];
    float lv = alv + bvar[i];
    out[(size_t)b * ZDIM + i] = mu + eps[(size_t)b * ZDIM + i] * __expf(0.5f * lv);
}

// ---------------------------------------------------------------------------
extern "C" void kernel_launch(void* const* d_in, const int* in_sizes, int n_in,
                              void* d_out, int out_size, void* d_ws, size_t ws_size,
                              hipStream_t stream) {
    const float* input = (const float*)d_in[0];
    const float* eps   = (const float*)d_in[1];
    const float* w_ih0 = (const float*)d_in[2];
    const float* w_hh0 = (const float*)d_in[3];
    const float* b_ih0 = (const float*)d_in[4];
    const float* b_hh0 = (const float*)d_in[5];
    const float* w_ih1 = (const float*)d_in[6];
    const float* w_hh1 = (const float*)d_in[7];
    const float* b_ih1 = (const float*)d_in[8];
    const float* b_hh1 = (const float*)d_in[9];
    const float* W_mu  = (const float*)d_in[10];
    const float* b_mu  = (const float*)d_in[11];
    const float* W_var = (const float*)d_in[12];
    const float* b_var = (const float*)d_in[13];
    float* out = (float*)d_out;

    uint8_t* base = (uint8_t*)d_ws;
    size_t off = 0;
    auto alloc = [&](size_t bytes) -> void* {
        void* p = base + off;
        off += (bytes + 255) & ~(size_t)255;
        return p;
    };
    unsigned short* xb   = (unsigned short*)alloc((size_t)TSTEPS * B * E * 2);  // 20.9 MB
    unsigned short* w0p  = (unsigned short*)alloc((size_t)2 * 2048 * E * 2);
    unsigned short* wh0p = (unsigned short*)alloc((size_t)2 * 2048 * H * 2);
    unsigned short* w1p  = (unsigned short*)alloc((size_t)2 * 2048 * 1024 * 2);
    unsigned short* wh1p = (unsigned short*)alloc((size_t)2 * 2048 * H * 2);
    float* b0p  = (float*)alloc(2 * 2048 * 4);
    float* b1p  = (float*)alloc(2 * 2048 * 4);
    unsigned short* hbuf = (unsigned short*)alloc((size_t)2 * 4 * HS * 2);
    float* cbuf = (float*)alloc((size_t)4 * HS * 4);

    // zero h (both bufs) and c — contiguous region
    hipMemsetAsync(hbuf, 0, (size_t)2 * 4 * HS * 2 + (size_t)4 * HS * 4, stream);

    // prep: bf16 conversions + gate-minor repack
    conv_x_kernel<<<(TSTEPS * B * E / 8 + 255) / 256, 256, 0, stream>>>(input, xb, TSTEPS * B * E / 8);
    repack_w_kernel<<<(2 * 2048 * (E / 8) + 255) / 256, 256, 0, stream>>>(w_ih0, w0p, E);
    repack_w_kernel<<<(2 * 2048 * (H / 8) + 255) / 256, 256, 0, stream>>>(w_hh0, wh0p, H);
    repack_w_kernel<<<(2 * 2048 * (1024 / 8) + 255) / 256, 256, 0, stream>>>(w_ih1, w1p, 1024);
    repack_w_kernel<<<(2 * 2048 * (H / 8) + 255) / 256, 256, 0, stream>>>(w_hh1, wh1p, H);
    pack_bias_kernel<<<16, 256, 0, stream>>>(b_ih0, b_hh0, b0p);
    pack_bias_kernel<<<16, 256, 0, stream>>>(b_ih1, b_hh1, b1p);

    // pipelined recurrence: kernel k does L0(t=k) and L1(t=k-1)
    for (int k = 0; k < TSTEPS + 1; ++k) {
        step_kernel<<<256, 256, 0, stream>>>(xb, w0p, wh0p, w1p, wh1p, b0p, b1p, hbuf, cbuf, k);
    }

    head_kernel<<<ZDIM / 4, 256, 0, stream>>>(hbuf, cbuf, eps, W_mu, b_mu, W_var, b_var, out);
}